// Round 1
// baseline (1337.071 us; speedup 1.0000x reference)
//
#include <hip/hip_runtime.h>
#include <float.h>

#define BB 4
#define SS 2048
#define HH 4
#define DHH 48
#define DD 192
#define QT 16
#define KTILE 256
#define NEG_BIG (-1e9f)

// ---------------------------------------------------------------------------
// Projection: Y[row][j] = sum_c X[row][c] * W[j][c]   (i.e. Y = X @ W^T)
// X: (R,192) fp32, W: (192,192) fp32, Y: (R,192) fp32
// block = 192 threads, 16 rows/block; thread owns a 4x4 (row x col) tile.
// ---------------------------------------------------------------------------
__global__ __launch_bounds__(192) void proj_kernel(
    const float* __restrict__ X, const float* __restrict__ W,
    float* __restrict__ Y)
{
    __shared__ __align__(16) float xs[QT][DD];
    const int row0 = blockIdx.x * QT;
    const int t = threadIdx.x;

    for (int idx = t; idx < QT * DD; idx += 192)
        xs[idx / DD][idx % DD] = X[(size_t)(row0 + idx / DD) * DD + idx % DD];
    __syncthreads();

    const int jt = (t % 48) * 4;   // 4 output cols
    const int rt = (t / 48) * 4;   // 4 rows

    float acc[4][4];
#pragma unroll
    for (int r = 0; r < 4; ++r)
#pragma unroll
        for (int j = 0; j < 4; ++j) acc[r][j] = 0.f;

#pragma unroll 4
    for (int c4 = 0; c4 < DD / 4; ++c4) {
        float4 xv[4], wv[4];
#pragma unroll
        for (int r = 0; r < 4; ++r)
            xv[r] = *(const float4*)&xs[rt + r][c4 * 4];
#pragma unroll
        for (int j = 0; j < 4; ++j)
            wv[j] = *(const float4*)&W[(size_t)(jt + j) * DD + c4 * 4];
#pragma unroll
        for (int r = 0; r < 4; ++r)
#pragma unroll
            for (int j = 0; j < 4; ++j) {
                acc[r][j] = fmaf(xv[r].x, wv[j].x, acc[r][j]);
                acc[r][j] = fmaf(xv[r].y, wv[j].y, acc[r][j]);
                acc[r][j] = fmaf(xv[r].z, wv[j].z, acc[r][j]);
                acc[r][j] = fmaf(xv[r].w, wv[j].w, acc[r][j]);
            }
    }

#pragma unroll
    for (int r = 0; r < 4; ++r) {
        float4 o = make_float4(acc[r][0], acc[r][1], acc[r][2], acc[r][3]);
        *(float4*)&Y[(size_t)(row0 + rt + r) * DD + jt] = o;
    }
}

// ---------------------------------------------------------------------------
// Fused attention: per (b, 16-row q tile).
// Two passes over K: pass1 = online softmax stats (m,l) with wave-butterfly
// reduce; pass2 = recompute logits -> weights, write mean-over-heads row,
// stage W tile in LDS [h][r][kk] (contiguous b128 writes), PV accumulate.
// q/k/v stay in plain (b,s,192) layout; head = 48-col slice.
// block = 256 threads (4 waves); wave owns 4 q rows; lane owns 4 consecutive
// kk per 256-wide K tile.
// ---------------------------------------------------------------------------
__global__ __launch_bounds__(256, 2) void attn_kernel(
    const float* __restrict__ qw, const float* __restrict__ kw,
    const float* __restrict__ vw, const int* __restrict__ mask,
    const float* __restrict__ bias,
    float* __restrict__ out1,   // (b,s,s) mean weights
    float* __restrict__ oattn)  // (b,s,192) pre-Wo attention output
{
    __shared__ __align__(16) float q_s[QT][DD];          // 12.3 KB
    __shared__ __align__(16) float w_s[HH][QT][KTILE];   // 64 KB

    const int b  = blockIdx.x / (SS / QT);
    const int q0 = (blockIdx.x % (SS / QT)) * QT;
    const int t = threadIdx.x;
    const int wave = t >> 6;
    const int lane = t & 63;

    for (int idx = t; idx < QT * DD; idx += 256)
        q_s[idx / DD][idx % DD] =
            qw[(size_t)(b * SS + q0 + idx / DD) * DD + idx % DD];
    __syncthreads();

    float m_[4][4], l_[4][4];   // [r][h] running max / denom
#pragma unroll
    for (int r = 0; r < 4; ++r)
#pragma unroll
        for (int h = 0; h < 4; ++h) { m_[r][h] = -FLT_MAX; l_[r][h] = 0.f; }

    // ---------------- PASS 1: softmax stats ----------------
    for (int kt = 0; kt < SS / KTILE; ++kt) {
        const int kk0 = kt * KTILE + lane * 4;
        int4 mz[4];
#pragma unroll
        for (int r = 0; r < 4; ++r)
            mz[r] = *(const int4*)&mask[(size_t)(b * SS + q0 + wave * 4 + r) * SS + kk0];

#pragma unroll
        for (int h = 0; h < 4; ++h) {
            float acc[4][4];
#pragma unroll
            for (int r = 0; r < 4; ++r)
#pragma unroll
                for (int i = 0; i < 4; ++i) acc[r][i] = 0.f;

            const float* kb = kw + (size_t)(b * SS + kk0) * DD + h * DHH;
#pragma unroll 4
            for (int c4 = 0; c4 < 12; ++c4) {
                float4 kv[4], qv[4];
#pragma unroll
                for (int i = 0; i < 4; ++i)
                    kv[i] = *(const float4*)(kb + (size_t)i * DD + c4 * 4);
#pragma unroll
                for (int r = 0; r < 4; ++r)
                    qv[r] = *(const float4*)&q_s[wave * 4 + r][h * DHH + c4 * 4];
#pragma unroll
                for (int r = 0; r < 4; ++r)
#pragma unroll
                    for (int i = 0; i < 4; ++i) {
                        acc[r][i] = fmaf(qv[r].x, kv[i].x, acc[r][i]);
                        acc[r][i] = fmaf(qv[r].y, kv[i].y, acc[r][i]);
                        acc[r][i] = fmaf(qv[r].z, kv[i].z, acc[r][i]);
                        acc[r][i] = fmaf(qv[r].w, kv[i].w, acc[r][i]);
                    }
            }

#pragma unroll
            for (int r = 0; r < 4; ++r) {
                float4 bv = *(const float4*)&bias[(size_t)(h * SS + q0 + wave * 4 + r) * SS + kk0];
                const int* mp = (const int*)&mz[r];
                float lg0 = mp[0] ? acc[r][0] + bv.x : NEG_BIG;
                float lg1 = mp[1] ? acc[r][1] + bv.y : NEG_BIG;
                float lg2 = mp[2] ? acc[r][2] + bv.z : NEG_BIG;
                float lg3 = mp[3] ? acc[r][3] + bv.w : NEG_BIG;
                float mx = fmaxf(fmaxf(lg0, lg1), fmaxf(lg2, lg3));
                float mo = m_[r][h];
                float mn = fmaxf(mo, mx);
                float s4 = __expf(lg0 - mn) + __expf(lg1 - mn) +
                           __expf(lg2 - mn) + __expf(lg3 - mn);
                l_[r][h] = l_[r][h] * __expf(mo - mn) + s4;
                m_[r][h] = mn;
            }
        }
    }

    // wave butterfly reduce of (m,l) across 64 lanes; then l := 1/l
#pragma unroll
    for (int r = 0; r < 4; ++r)
#pragma unroll
        for (int h = 0; h < 4; ++h) {
            float mm = m_[r][h], ll = l_[r][h];
#pragma unroll
            for (int off = 32; off > 0; off >>= 1) {
                float mo = __shfl_xor(mm, off);
                float lo = __shfl_xor(ll, off);
                float mn = fmaxf(mm, mo);
                ll = ll * __expf(mm - mn) + lo * __expf(mo - mn);
                mm = mn;
            }
            m_[r][h] = mm;
            l_[r][h] = 1.0f / ll;
        }

    // ---------------- PASS 2: weights + mean + PV ----------------
    float pacc[QT];
#pragma unroll
    for (int r = 0; r < QT; ++r) pacc[r] = 0.f;

    for (int kt = 0; kt < SS / KTILE; ++kt) {
        const int kk0 = kt * KTILE + lane * 4;
        int4 mz[4];
#pragma unroll
        for (int r = 0; r < 4; ++r)
            mz[r] = *(const int4*)&mask[(size_t)(b * SS + q0 + wave * 4 + r) * SS + kk0];

        float wsum[4][4];
#pragma unroll
        for (int r = 0; r < 4; ++r)
#pragma unroll
            for (int i = 0; i < 4; ++i) wsum[r][i] = 0.f;

        __syncthreads();   // previous PV finished reading w_s

#pragma unroll
        for (int h = 0; h < 4; ++h) {
            float acc[4][4];
#pragma unroll
            for (int r = 0; r < 4; ++r)
#pragma unroll
                for (int i = 0; i < 4; ++i) acc[r][i] = 0.f;

            const float* kb = kw + (size_t)(b * SS + kk0) * DD + h * DHH;
#pragma unroll 4
            for (int c4 = 0; c4 < 12; ++c4) {
                float4 kv[4], qv[4];
#pragma unroll
                for (int i = 0; i < 4; ++i)
                    kv[i] = *(const float4*)(kb + (size_t)i * DD + c4 * 4);
#pragma unroll
                for (int r = 0; r < 4; ++r)
                    qv[r] = *(const float4*)&q_s[wave * 4 + r][h * DHH + c4 * 4];
#pragma unroll
                for (int r = 0; r < 4; ++r)
#pragma unroll
                    for (int i = 0; i < 4; ++i) {
                        acc[r][i] = fmaf(qv[r].x, kv[i].x, acc[r][i]);
                        acc[r][i] = fmaf(qv[r].y, kv[i].y, acc[r][i]);
                        acc[r][i] = fmaf(qv[r].z, kv[i].z, acc[r][i]);
                        acc[r][i] = fmaf(qv[r].w, kv[i].w, acc[r][i]);
                    }
            }

#pragma unroll
            for (int r = 0; r < 4; ++r) {
                float4 bv = *(const float4*)&bias[(size_t)(h * SS + q0 + wave * 4 + r) * SS + kk0];
                const int* mp = (const int*)&mz[r];
                float lg0 = mp[0] ? acc[r][0] + bv.x : NEG_BIG;
                float lg1 = mp[1] ? acc[r][1] + bv.y : NEG_BIG;
                float lg2 = mp[2] ? acc[r][2] + bv.z : NEG_BIG;
                float lg3 = mp[3] ? acc[r][3] + bv.w : NEG_BIG;
                float w0 = __expf(lg0 - m_[r][h]) * l_[r][h];
                float w1 = __expf(lg1 - m_[r][h]) * l_[r][h];
                float w2 = __expf(lg2 - m_[r][h]) * l_[r][h];
                float w3 = __expf(lg3 - m_[r][h]) * l_[r][h];
                *(float4*)&w_s[h][wave * 4 + r][lane * 4] = make_float4(w0, w1, w2, w3);
                wsum[r][0] += w0; wsum[r][1] += w1;
                wsum[r][2] += w2; wsum[r][3] += w3;
            }
        }

        // mean over heads -> out1 (coalesced float4 per row)
#pragma unroll
        for (int r = 0; r < 4; ++r) {
            float4 o1 = make_float4(wsum[r][0] * 0.25f, wsum[r][1] * 0.25f,
                                    wsum[r][2] * 0.25f, wsum[r][3] * 0.25f);
            *(float4*)&out1[(size_t)(b * SS + q0 + wave * 4 + r) * SS + kk0] = o1;
        }

        __syncthreads();   // w_s tile complete

        // PV: threads 0..191 -> (head, jj); each accumulates all 16 rows
        if (t < 192) {
            const int ph = t / DHH;
            const int pj = t % DHH;
            const float* vb = vw + (size_t)(b * SS + kt * KTILE) * DD + ph * DHH + pj;
#pragma unroll 4
            for (int k2 = 0; k2 < KTILE; k2 += 4) {
                float v0 = vb[(size_t)(k2 + 0) * DD];
                float v1 = vb[(size_t)(k2 + 1) * DD];
                float v2 = vb[(size_t)(k2 + 2) * DD];
                float v3 = vb[(size_t)(k2 + 3) * DD];
#pragma unroll
                for (int r = 0; r < QT; ++r) {
                    float4 w4 = *(const float4*)&w_s[ph][r][k2];
                    pacc[r] = fmaf(w4.x, v0, pacc[r]);
                    pacc[r] = fmaf(w4.y, v1, pacc[r]);
                    pacc[r] = fmaf(w4.z, v2, pacc[r]);
                    pacc[r] = fmaf(w4.w, v3, pacc[r]);
                }
            }
        }
    }

    if (t < 192) {
#pragma unroll
        for (int r = 0; r < QT; ++r)
            oattn[(size_t)(b * SS + q0 + r) * DD + t] = pacc[r];
    }
}

// ---------------------------------------------------------------------------
extern "C" void kernel_launch(void* const* d_in, const int* in_sizes, int n_in,
                              void* d_out, int out_size, void* d_ws, size_t ws_size,
                              hipStream_t stream)
{
    const float* query = (const float*)d_in[0];
    const float* key   = (const float*)d_in[1];
    const float* value = (const float*)d_in[2];
    const int*   amask = (const int*)d_in[3];
    const float* bias  = (const float*)d_in[4];
    const float* Wq    = (const float*)d_in[5];
    const float* Wk    = (const float*)d_in[6];
    const float* Wv    = (const float*)d_in[7];
    const float* Wo    = (const float*)d_in[8];

    const size_t n_qkv = (size_t)BB * SS * DD;   // 1,572,864
    float* out0 = (float*)d_out;                 // (b,s,192)
    float* out1 = out0 + n_qkv;                  // (b,s,s)

    float* ws    = (float*)d_ws;
    float* qws   = ws;
    float* kws   = ws + n_qkv;
    float* vws   = ws + 2 * n_qkv;
    float* oattn = ws + 3 * n_qkv;               // total 25.2 MB of d_ws

    const dim3 pgrid(BB * SS / QT);  // 512 blocks
    proj_kernel<<<pgrid, 192, 0, stream>>>(query, Wq, qws);
    proj_kernel<<<pgrid, 192, 0, stream>>>(key,   Wk, kws);
    proj_kernel<<<pgrid, 192, 0, stream>>>(value, Wv, vws);

    attn_kernel<<<dim3(BB * SS / QT), 256, 0, stream>>>(qws, kws, vws, amask,
                                                        bias, out1, oattn);

    proj_kernel<<<pgrid, 192, 0, stream>>>(oattn, Wo, out0);
}

// Round 2
// 1029.319 us; speedup vs baseline: 1.2990x; 1.2990x over previous
//
#include <hip/hip_runtime.h>

#define BB 4
#define SS 2048
#define HH 4
#define DD 192
#define QT 16
#define NEG_BIG (-1e9f)

typedef __attribute__((ext_vector_type(8))) short short8;
typedef __attribute__((ext_vector_type(4))) float f32x4;

__device__ inline ushort f2bf(float x) {
    union { float f; unsigned u; } v; v.f = x;
    unsigned r = (v.u + 0x7FFFu + ((v.u >> 16) & 1u)) >> 16;
    return (ushort)r;
}
__device__ inline float bf2f(ushort x) {
    union { unsigned u; float f; } v; v.u = ((unsigned)x) << 16;
    return v.f;
}

// ---------------------------------------------------------------------------
// Fused QKV projection. Y = X @ W^T computed in fp32, emitted as bf16 in
// MFMA-friendly layouts:
//   mode 0/1 (q/k): (b,s,h,64) bf16, feature 48..63 zero-padded
//   mode 2   (v)  : transposed (b,h,48,s) bf16
// block = 384 threads (6 waves), 16 rows; thread tile = 2 rows x 4 cols.
// ---------------------------------------------------------------------------
__global__ __launch_bounds__(384) void qkv_proj_kernel(
    const float* __restrict__ Xq, const float* __restrict__ Xk,
    const float* __restrict__ Xv,
    const float* __restrict__ Wq, const float* __restrict__ Wk,
    const float* __restrict__ Wv,
    ushort* __restrict__ qpad, ushort* __restrict__ kpad,
    ushort* __restrict__ vT)
{
    const int mode = blockIdx.y;
    const float* __restrict__ X = (mode == 0) ? Xq : (mode == 1) ? Xk : Xv;
    const float* __restrict__ W = (mode == 0) ? Wq : (mode == 1) ? Wk : Wv;

    __shared__ __align__(16) float xs[QT][DD];
    const int row0 = blockIdx.x * QT;
    const int t = threadIdx.x;
    for (int idx = t; idx < QT * DD; idx += 384)
        xs[idx / DD][idx % DD] = X[(size_t)(row0 + idx / DD) * DD + idx % DD];
    __syncthreads();

    const int jt = (t % 48) * 4;   // 4 output cols
    const int rt = (t / 48) * 2;   // 2 rows

    float acc[2][4];
#pragma unroll
    for (int r = 0; r < 2; ++r)
#pragma unroll
        for (int j = 0; j < 4; ++j) acc[r][j] = 0.f;

#pragma unroll 4
    for (int c4 = 0; c4 < DD / 4; ++c4) {
        float4 xv0 = *(const float4*)&xs[rt][c4 * 4];
        float4 xv1 = *(const float4*)&xs[rt + 1][c4 * 4];
        float4 wv[4];
#pragma unroll
        for (int j = 0; j < 4; ++j)
            wv[j] = *(const float4*)&W[(size_t)(jt + j) * DD + c4 * 4];
#pragma unroll
        for (int j = 0; j < 4; ++j) {
            acc[0][j] = fmaf(xv0.x, wv[j].x, acc[0][j]);
            acc[0][j] = fmaf(xv0.y, wv[j].y, acc[0][j]);
            acc[0][j] = fmaf(xv0.z, wv[j].z, acc[0][j]);
            acc[0][j] = fmaf(xv0.w, wv[j].w, acc[0][j]);
            acc[1][j] = fmaf(xv1.x, wv[j].x, acc[1][j]);
            acc[1][j] = fmaf(xv1.y, wv[j].y, acc[1][j]);
            acc[1][j] = fmaf(xv1.z, wv[j].z, acc[1][j]);
            acc[1][j] = fmaf(xv1.w, wv[j].w, acc[1][j]);
        }
    }

    if (mode < 2) {
        ushort* __restrict__ out = (mode == 0) ? qpad : kpad;
        const int h = jt / 48, f = jt % 48;
#pragma unroll
        for (int r = 0; r < 2; ++r) {
            ushort4 o;
            o.x = f2bf(acc[r][0]); o.y = f2bf(acc[r][1]);
            o.z = f2bf(acc[r][2]); o.w = f2bf(acc[r][3]);
            *(ushort4*)&out[((size_t)(row0 + rt + r) * HH + h) * 64 + f] = o;
        }
        // zero the pad region f=48..63 (ws is re-poisoned before every launch)
        if (t < 128) {
            const int row = t >> 3, hh = (t >> 1) & 3, half = t & 1;
            int4 z = make_int4(0, 0, 0, 0);
            *(int4*)&out[((size_t)(row0 + row) * HH + hh) * 64 + 48 + half * 8] = z;
        }
    } else {
        const int b = row0 >> 11, s0 = row0 & (SS - 1);
#pragma unroll
        for (int j = 0; j < 4; ++j) {
            const int col = jt + j, h = col / 48, f = col % 48;
            unsigned pk = (unsigned)f2bf(acc[0][j]) |
                          ((unsigned)f2bf(acc[1][j]) << 16);
            *(unsigned*)&vT[((size_t)(b * HH + h) * 48 + f) * SS + s0 + rt] = pk;
        }
    }
}

// ---------------------------------------------------------------------------
// Output projection (fp32): out0 = oattn @ Wo^T. Same threading as above.
// ---------------------------------------------------------------------------
__global__ __launch_bounds__(384) void o_proj_kernel(
    const float* __restrict__ X, const float* __restrict__ W,
    float* __restrict__ Y)
{
    __shared__ __align__(16) float xs[QT][DD];
    const int row0 = blockIdx.x * QT;
    const int t = threadIdx.x;
    for (int idx = t; idx < QT * DD; idx += 384)
        xs[idx / DD][idx % DD] = X[(size_t)(row0 + idx / DD) * DD + idx % DD];
    __syncthreads();

    const int jt = (t % 48) * 4;
    const int rt = (t / 48) * 2;

    float acc[2][4];
#pragma unroll
    for (int r = 0; r < 2; ++r)
#pragma unroll
        for (int j = 0; j < 4; ++j) acc[r][j] = 0.f;

#pragma unroll 4
    for (int c4 = 0; c4 < DD / 4; ++c4) {
        float4 xv0 = *(const float4*)&xs[rt][c4 * 4];
        float4 xv1 = *(const float4*)&xs[rt + 1][c4 * 4];
        float4 wv[4];
#pragma unroll
        for (int j = 0; j < 4; ++j)
            wv[j] = *(const float4*)&W[(size_t)(jt + j) * DD + c4 * 4];
#pragma unroll
        for (int j = 0; j < 4; ++j) {
            acc[0][j] = fmaf(xv0.x, wv[j].x, acc[0][j]);
            acc[0][j] = fmaf(xv0.y, wv[j].y, acc[0][j]);
            acc[0][j] = fmaf(xv0.z, wv[j].z, acc[0][j]);
            acc[0][j] = fmaf(xv0.w, wv[j].w, acc[0][j]);
            acc[1][j] = fmaf(xv1.x, wv[j].x, acc[1][j]);
            acc[1][j] = fmaf(xv1.y, wv[j].y, acc[1][j]);
            acc[1][j] = fmaf(xv1.z, wv[j].z, acc[1][j]);
            acc[1][j] = fmaf(xv1.w, wv[j].w, acc[1][j]);
        }
    }

#pragma unroll
    for (int r = 0; r < 2; ++r)
        *(float4*)&Y[(size_t)(row0 + rt + r) * DD + jt] =
            make_float4(acc[r][0], acc[r][1], acc[r][2], acc[r][3]);
}

// ---------------------------------------------------------------------------
// MFMA attention. Block = (b, 16-row q-tile); 4 waves = 4 heads.
// Max-free softmax (|logit| <= ~45 << 88 overflow): pass 1 accumulates
// l = sum(exp) only; pass 2 recomputes bit-identical logits, writes
// w = exp * (1/l) to LDS (bf16, A-operand layout), reduces heads -> out1,
// and PV-accumulates via MFMA from vT.
// MFMA 16x16x32 bf16: A[m=lane&15][k=quad*8+j]; B[k=quad*8+j][n=lane&15];
// D: col=lane&15, row=quad*4+reg.
// ---------------------------------------------------------------------------
__device__ inline f32x4 qk_tile(const ushort* kp, short8 qa0, short8 qa1) {
    short8 kb0 = *(const short8*)(kp);
    short8 kb1 = *(const short8*)(kp + 32);
    f32x4 d = {0.f, 0.f, 0.f, 0.f};
    d = __builtin_amdgcn_mfma_f32_16x16x32_bf16(qa0, kb0, d, 0, 0, 0);
    d = __builtin_amdgcn_mfma_f32_16x16x32_bf16(qa1, kb1, d, 0, 0, 0);
    return d;
}

__global__ __launch_bounds__(256) void attn_kernel(
    const ushort* __restrict__ qpad, const ushort* __restrict__ kpad,
    const ushort* __restrict__ vT, const int* __restrict__ mask,
    const float* __restrict__ bias,
    float* __restrict__ out1, float* __restrict__ oattn)
{
    // w tile in bf16, row stride 72 (144B = 16B-aligned, 2-way-bank only)
    __shared__ __align__(16) ushort w_lds[HH][QT][72];   // 9216 B

    const int b  = blockIdx.x >> 7;
    const int q0 = (blockIdx.x & 127) * QT;
    const int t = threadIdx.x;
    const int h = t >> 6, lane = t & 63;
    const int n16 = lane & 15, quad = lane >> 4;

    // Q fragment (A-operand), two 32-feature chunks, resident all kernel
    const ushort* qbase =
        qpad + ((size_t)(b * SS + q0 + n16) * HH + h) * 64 + quad * 8;
    const short8 qa0 = *(const short8*)(qbase);
    const short8 qa1 = *(const short8*)(qbase + 32);

    const ushort* kbase = kpad + ((size_t)b * SS * HH) * 64 + h * 64 + quad * 8;
    const int* mrow = mask + ((size_t)(b * SS + q0 + quad * 4)) * SS;
    const float* brow = bias + ((size_t)(h * SS + q0 + quad * 4)) * SS;

    // ---------------- PASS 1: denominators ----------------
    float l_[4] = {0.f, 0.f, 0.f, 0.f};
    for (int kt = 0; kt < SS / 64; ++kt) {
        const int key0 = kt * 64;
#pragma unroll
        for (int g = 0; g < 4; ++g) {
            const int key = key0 + g * 16 + n16;
            f32x4 d = qk_tile(kbase + (size_t)key * (HH * 64), qa0, qa1);
#pragma unroll
            for (int r = 0; r < 4; ++r) {
                const int mz = mrow[(size_t)r * SS + key];
                const float bv = brow[(size_t)r * SS + key];
                const float lg = mz ? d[r] + bv : NEG_BIG;
                l_[r] += __expf(lg);
            }
        }
    }
    // reduce l over the 16 lanes sharing a quad (each holds keys == n16 mod 16)
    float linv[4];
#pragma unroll
    for (int r = 0; r < 4; ++r) {
        float ll = l_[r];
#pragma unroll
        for (int off = 1; off < 16; off <<= 1)
            ll += __shfl_xor(ll, off);
        linv[r] = 1.0f / ll;
    }

    // ---------------- PASS 2: weights, mean, PV ----------------
    f32x4 pv[3];
#pragma unroll
    for (int nb = 0; nb < 3; ++nb) pv[nb] = (f32x4){0.f, 0.f, 0.f, 0.f};

    for (int kt = 0; kt < SS / 64; ++kt) {
        const int key0 = kt * 64;
#pragma unroll
        for (int g = 0; g < 4; ++g) {
            const int key = key0 + g * 16 + n16;
            f32x4 d = qk_tile(kbase + (size_t)key * (HH * 64), qa0, qa1);
#pragma unroll
            for (int r = 0; r < 4; ++r) {
                const int mz = mrow[(size_t)r * SS + key];
                const float bv = brow[(size_t)r * SS + key];
                const float lg = mz ? d[r] + bv : NEG_BIG;
                const float w = __expf(lg) * linv[r];
                w_lds[h][quad * 4 + r][g * 16 + n16] = f2bf(w);
            }
        }
        __syncthreads();

        // mean over heads -> out1 (fp32), 256 threads x 4 iters = 16x64 tile
        {
            const int key = t & 63;
            const int rbase = t >> 6;
#pragma unroll
            for (int rr = 0; rr < 4; ++rr) {
                const int row = rr * 4 + rbase;
                float s = bf2f(w_lds[0][row][key]) + bf2f(w_lds[1][row][key]) +
                          bf2f(w_lds[2][row][key]) + bf2f(w_lds[3][row][key]);
                out1[((size_t)(b * SS + q0 + row)) * SS + key0 + key] = s * 0.25f;
            }
        }

        // PV: A = w tile (LDS), B = vT slices
        const short8 wa0 = *(const short8*)&w_lds[h][n16][quad * 8];
        const short8 wa1 = *(const short8*)&w_lds[h][n16][32 + quad * 8];
#pragma unroll
        for (int nb = 0; nb < 3; ++nb) {
            const ushort* vb =
                vT + ((size_t)(b * HH + h) * 48 + nb * 16 + n16) * SS +
                key0 + quad * 8;
            short8 v0 = *(const short8*)(vb);
            short8 v1 = *(const short8*)(vb + 32);
            pv[nb] = __builtin_amdgcn_mfma_f32_16x16x32_bf16(wa0, v0, pv[nb], 0, 0, 0);
            pv[nb] = __builtin_amdgcn_mfma_f32_16x16x32_bf16(wa1, v1, pv[nb], 0, 0, 0);
        }
        __syncthreads();
    }

#pragma unroll
    for (int nb = 0; nb < 3; ++nb)
#pragma unroll
        for (int r = 0; r < 4; ++r)
            oattn[((size_t)(b * SS + q0 + quad * 4 + r)) * DD +
                  h * 48 + nb * 16 + n16] = pv[nb][r];
}

// ---------------------------------------------------------------------------
extern "C" void kernel_launch(void* const* d_in, const int* in_sizes, int n_in,
                              void* d_out, int out_size, void* d_ws, size_t ws_size,
                              hipStream_t stream)
{
    const float* query = (const float*)d_in[0];
    const float* key   = (const float*)d_in[1];
    const float* value = (const float*)d_in[2];
    const int*   amask = (const int*)d_in[3];
    const float* bias  = (const float*)d_in[4];
    const float* Wq    = (const float*)d_in[5];
    const float* Wk    = (const float*)d_in[6];
    const float* Wv    = (const float*)d_in[7];
    const float* Wo    = (const float*)d_in[8];

    const size_t n_rows = (size_t)BB * SS;           // 8192
    float* out0 = (float*)d_out;                     // (b,s,192)
    float* out1 = out0 + n_rows * DD;                // (b,s,s)

    ushort* qpad = (ushort*)d_ws;                    // 4 MB
    ushort* kpad = qpad + n_rows * HH * 64;          // 4 MB
    ushort* vT   = kpad + n_rows * HH * 64;          // 3 MB
    float*  oattn = (float*)(vT + (size_t)BB * HH * 48 * SS);  // 6.3 MB fp32

    qkv_proj_kernel<<<dim3(BB * SS / QT, 3), 384, 0, stream>>>(
        query, key, value, Wq, Wk, Wv, qpad, kpad, vT);

    attn_kernel<<<dim3(BB * SS / QT), 256, 0, stream>>>(
        qpad, kpad, vT, amask, bias, out1, oattn);

    o_proj_kernel<<<dim3(BB * SS / QT), 384, 0, stream>>>(oattn, Wo, out0);
}

// Round 3
// 495.418 us; speedup vs baseline: 2.6989x; 2.0777x over previous
//
#include <hip/hip_runtime.h>

#define BB 4
#define SS 2048
#define HH 4
#define DD 192
#define QT 16
#define NEG_BIG (-1e9f)
#define MB_NEG 0xCE6Eu   // bf16(-1e9) approx

typedef __attribute__((ext_vector_type(8))) short short8;
typedef __attribute__((ext_vector_type(4))) float f32x4;

__device__ inline ushort f2bf(float x) {
    union { float f; unsigned u; } v; v.f = x;
    unsigned r = (v.u + 0x7FFFu + ((v.u >> 16) & 1u)) >> 16;
    return (ushort)r;
}
__device__ inline float bf2f(ushort x) {
    union { unsigned u; float f; } v; v.u = ((unsigned)x) << 16;
    return v.f;
}
// wave-local fence: all prior ds_writes visible to all lanes of this wave
__device__ inline void wave_lds_fence() {
    __builtin_amdgcn_wave_barrier();
    __builtin_amdgcn_s_waitcnt(0xC07F);   // vmcnt(63) expcnt(7) lgkmcnt(0)
    __builtin_amdgcn_wave_barrier();
}

// ---------------------------------------------------------------------------
// Transpose the four weight matrices: WT[c][j] = W[j][c].  grid (6,6,4).
// ---------------------------------------------------------------------------
__global__ __launch_bounds__(256) void wt_kernel(
    const float* __restrict__ Wq, const float* __restrict__ Wk,
    const float* __restrict__ Wv, const float* __restrict__ Wo,
    float* __restrict__ WTall)
{
    __shared__ float tile[32][33];
    const float* W = (blockIdx.z == 0) ? Wq : (blockIdx.z == 1) ? Wk
                   : (blockIdx.z == 2) ? Wv : Wo;
    float* WT = WTall + (size_t)blockIdx.z * DD * DD;
    const int c0 = blockIdx.x * 32, j0 = blockIdx.y * 32;
    const int tx = threadIdx.x & 31, ty = threadIdx.x >> 5;
#pragma unroll
    for (int k = 0; k < 4; ++k)
        tile[ty + 8 * k][tx] = W[(size_t)(j0 + ty + 8 * k) * DD + c0 + tx];
    __syncthreads();
#pragma unroll
    for (int k = 0; k < 4; ++k)
        WT[(size_t)(c0 + ty + 8 * k) * DD + j0 + tx] = tile[tx][ty + 8 * k];
}

// ---------------------------------------------------------------------------
// Fused QKV projection via WT (coalesced). 192 thr, 32 rows/block, grid(256,3).
// Thread: cols jt..jt+3, rows rowg*8..rowg*8+7.  Emits bf16 q/k padded or vT.
// ---------------------------------------------------------------------------
__global__ __launch_bounds__(192) void qkv_proj_kernel(
    const float* __restrict__ Xq, const float* __restrict__ Xk,
    const float* __restrict__ Xv, const float* __restrict__ WTall,
    ushort* __restrict__ qpad, ushort* __restrict__ kpad,
    ushort* __restrict__ vT)
{
    const int mode = blockIdx.y;
    const float* __restrict__ X = (mode == 0) ? Xq : (mode == 1) ? Xk : Xv;
    const float* __restrict__ WT = WTall + (size_t)mode * DD * DD;

    __shared__ __align__(16) float xs[32][DD];   // 24 KB
    const int row0 = blockIdx.x * 32;
    const int t = threadIdx.x;
    {
        const float4* src = (const float4*)(X + (size_t)row0 * DD);
        float4* dst = (float4*)&xs[0][0];
        for (int i = t; i < 32 * DD / 4; i += 192) dst[i] = src[i];
    }
    __syncthreads();

    const int jt = (t % 48) * 4;
    const int rowg = t / 48;           // 0..3, rows rowg*8 .. rowg*8+7

    float acc[8][4];
#pragma unroll
    for (int r = 0; r < 8; ++r)
#pragma unroll
        for (int j = 0; j < 4; ++j) acc[r][j] = 0.f;

#pragma unroll 2
    for (int k4 = 0; k4 < DD / 4; ++k4) {
        float4 w0 = *(const float4*)&WT[(size_t)(k4 * 4 + 0) * DD + jt];
        float4 w1 = *(const float4*)&WT[(size_t)(k4 * 4 + 1) * DD + jt];
        float4 w2 = *(const float4*)&WT[(size_t)(k4 * 4 + 2) * DD + jt];
        float4 w3 = *(const float4*)&WT[(size_t)(k4 * 4 + 3) * DD + jt];
#pragma unroll
        for (int r = 0; r < 8; ++r) {
            float4 xv = *(const float4*)&xs[rowg * 8 + r][k4 * 4];
            acc[r][0] = fmaf(xv.x, w0.x, acc[r][0]); acc[r][1] = fmaf(xv.x, w0.y, acc[r][1]);
            acc[r][2] = fmaf(xv.x, w0.z, acc[r][2]); acc[r][3] = fmaf(xv.x, w0.w, acc[r][3]);
            acc[r][0] = fmaf(xv.y, w1.x, acc[r][0]); acc[r][1] = fmaf(xv.y, w1.y, acc[r][1]);
            acc[r][2] = fmaf(xv.y, w1.z, acc[r][2]); acc[r][3] = fmaf(xv.y, w1.w, acc[r][3]);
            acc[r][0] = fmaf(xv.z, w2.x, acc[r][0]); acc[r][1] = fmaf(xv.z, w2.y, acc[r][1]);
            acc[r][2] = fmaf(xv.z, w2.z, acc[r][2]); acc[r][3] = fmaf(xv.z, w2.w, acc[r][3]);
            acc[r][0] = fmaf(xv.w, w3.x, acc[r][0]); acc[r][1] = fmaf(xv.w, w3.y, acc[r][1]);
            acc[r][2] = fmaf(xv.w, w3.z, acc[r][2]); acc[r][3] = fmaf(xv.w, w3.w, acc[r][3]);
        }
    }

    if (mode < 2) {
        ushort* __restrict__ out = (mode == 0) ? qpad : kpad;
        const int hd = jt / 48, f = jt % 48;
#pragma unroll
        for (int r = 0; r < 8; ++r) {
            ushort4 o;
            o.x = f2bf(acc[r][0]); o.y = f2bf(acc[r][1]);
            o.z = f2bf(acc[r][2]); o.w = f2bf(acc[r][3]);
            *(ushort4*)&out[((size_t)(row0 + rowg * 8 + r) * HH + hd) * 64 + f] = o;
        }
        // zero pad f=48..63 for all 32 rows x 4 heads
        const int4 z = make_int4(0, 0, 0, 0);
        for (int i = t; i < 256; i += 192) {
            const int row = i >> 3, hh = (i >> 1) & 3, half = i & 1;
            *(int4*)&out[((size_t)(row0 + row) * HH + hh) * 64 + 48 + half * 8] = z;
        }
    } else {
        const int b = row0 >> 11, s0 = row0 & (SS - 1);
#pragma unroll
        for (int j = 0; j < 4; ++j) {
            const int col = jt + j, hd = col / 48, f = col % 48;
#pragma unroll
            for (int p = 0; p < 4; ++p) {
                unsigned pk = (unsigned)f2bf(acc[2 * p][j]) |
                              ((unsigned)f2bf(acc[2 * p + 1][j]) << 16);
                *(unsigned*)&vT[(((size_t)b * HH + hd) * 48 + f) * SS +
                                s0 + rowg * 8 + 2 * p] = pk;
            }
        }
    }
}

// ---------------------------------------------------------------------------
// Output projection via WoT (fp32 in/out). Same tiling as qkv_proj.
// ---------------------------------------------------------------------------
__global__ __launch_bounds__(192) void o_proj_kernel(
    const float* __restrict__ X, const float* __restrict__ WT,
    float* __restrict__ Y)
{
    __shared__ __align__(16) float xs[32][DD];
    const int row0 = blockIdx.x * 32;
    const int t = threadIdx.x;
    {
        const float4* src = (const float4*)(X + (size_t)row0 * DD);
        float4* dst = (float4*)&xs[0][0];
        for (int i = t; i < 32 * DD / 4; i += 192) dst[i] = src[i];
    }
    __syncthreads();

    const int jt = (t % 48) * 4;
    const int rowg = t / 48;

    float acc[8][4];
#pragma unroll
    for (int r = 0; r < 8; ++r)
#pragma unroll
        for (int j = 0; j < 4; ++j) acc[r][j] = 0.f;

#pragma unroll 2
    for (int k4 = 0; k4 < DD / 4; ++k4) {
        float4 w0 = *(const float4*)&WT[(size_t)(k4 * 4 + 0) * DD + jt];
        float4 w1 = *(const float4*)&WT[(size_t)(k4 * 4 + 1) * DD + jt];
        float4 w2 = *(const float4*)&WT[(size_t)(k4 * 4 + 2) * DD + jt];
        float4 w3 = *(const float4*)&WT[(size_t)(k4 * 4 + 3) * DD + jt];
#pragma unroll
        for (int r = 0; r < 8; ++r) {
            float4 xv = *(const float4*)&xs[rowg * 8 + r][k4 * 4];
            acc[r][0] = fmaf(xv.x, w0.x, acc[r][0]); acc[r][1] = fmaf(xv.x, w0.y, acc[r][1]);
            acc[r][2] = fmaf(xv.x, w0.z, acc[r][2]); acc[r][3] = fmaf(xv.x, w0.w, acc[r][3]);
            acc[r][0] = fmaf(xv.y, w1.x, acc[r][0]); acc[r][1] = fmaf(xv.y, w1.y, acc[r][1]);
            acc[r][2] = fmaf(xv.y, w1.z, acc[r][2]); acc[r][3] = fmaf(xv.y, w1.w, acc[r][3]);
            acc[r][0] = fmaf(xv.z, w2.x, acc[r][0]); acc[r][1] = fmaf(xv.z, w2.y, acc[r][1]);
            acc[r][2] = fmaf(xv.z, w2.z, acc[r][2]); acc[r][3] = fmaf(xv.z, w2.w, acc[r][3]);
            acc[r][0] = fmaf(xv.w, w3.x, acc[r][0]); acc[r][1] = fmaf(xv.w, w3.y, acc[r][1]);
            acc[r][2] = fmaf(xv.w, w3.z, acc[r][2]); acc[r][3] = fmaf(xv.w, w3.w, acc[r][3]);
        }
    }

#pragma unroll
    for (int r = 0; r < 8; ++r)
        *(float4*)&Y[(size_t)(row0 + rowg * 8 + r) * DD + jt] =
            make_float4(acc[r][0], acc[r][1], acc[r][2], acc[r][3]);
}

// ---------------------------------------------------------------------------
// MFMA attention, 8 waves: wave w -> head h=w&3, K-half kh=w>>2.
// Mask+bias pre-combined into per-wave LDS tile (bf16) with wide coalesced
// loads; exp path reads LDS.  l and PV partials merged across K-halves.
// ---------------------------------------------------------------------------
__device__ inline f32x4 qk_tile(const ushort* kp, short8 qa0, short8 qa1) {
    short8 kb0 = *(const short8*)(kp);
    short8 kb1 = *(const short8*)(kp + 32);
    f32x4 d = {0.f, 0.f, 0.f, 0.f};
    d = __builtin_amdgcn_mfma_f32_16x16x32_bf16(qa0, kb0, d, 0, 0, 0);
    d = __builtin_amdgcn_mfma_f32_16x16x32_bf16(qa1, kb1, d, 0, 0, 0);
    return d;
}

__global__ __launch_bounds__(512, 4) void attn_kernel(
    const ushort* __restrict__ qpad, const ushort* __restrict__ kpad,
    const ushort* __restrict__ vT, const int* __restrict__ mask,
    const float* __restrict__ bias,
    float* __restrict__ out1, float* __restrict__ oattn)
{
    __shared__ __align__(16) ushort mb[8][QT][68];     // 17408 B masked-bias bf16
    __shared__ __align__(16) ushort w_lds[8][QT][72];  // 18432 B weights bf16
    __shared__ float l_scr[8][QT];                     // 512 B

    const int b  = blockIdx.x >> 7;
    const int q0 = (blockIdx.x & 127) * QT;
    const int t = threadIdx.x;
    const int w = t >> 6;
    const int h = w & 3;
    const int kh = w >> 2;
    const int lane = t & 63;
    const int n16 = lane & 15, quad = lane >> 4;
    const int kbase0 = kh * (SS / 2);

    const ushort* qbase =
        qpad + ((size_t)(b * SS + q0 + n16) * HH + h) * 64 + quad * 8;
    const short8 qa0 = *(const short8*)(qbase);
    const short8 qa1 = *(const short8*)(qbase + 32);
    const ushort* kbase = kpad + (size_t)b * SS * HH * 64 + h * 64 + quad * 8;

    const int srow = lane >> 4;          // staging row base (+4*rr)
    const int skey = (lane & 15) * 4;    // staging key (float4/int4)
    const int* mrow0 = mask + (size_t)(b * SS + q0) * SS + kbase0 + skey;
    const float* brow0 = bias + (size_t)(h * SS + q0) * SS + kbase0 + skey;

    // ---------------- PASS 1: denominators ----------------
    float l_[4] = {0.f, 0.f, 0.f, 0.f};
    for (int kt = 0; kt < SS / 2 / 64; ++kt) {
        const int kb = kt * 64;
#pragma unroll
        for (int rr = 0; rr < 4; ++rr) {
            const int row = rr * 4 + srow;
            int4 mz = *(const int4*)(mrow0 + (size_t)row * SS + kb);
            float4 bv = *(const float4*)(brow0 + (size_t)row * SS + kb);
            ushort4 o;
            o.x = mz.x ? f2bf(bv.x) : (ushort)MB_NEG;
            o.y = mz.y ? f2bf(bv.y) : (ushort)MB_NEG;
            o.z = mz.z ? f2bf(bv.z) : (ushort)MB_NEG;
            o.w = mz.w ? f2bf(bv.w) : (ushort)MB_NEG;
            *(ushort4*)&mb[w][row][skey] = o;
        }
        wave_lds_fence();
#pragma unroll
        for (int g = 0; g < 4; ++g) {
            const int key = kbase0 + kb + g * 16 + n16;
            f32x4 d = qk_tile(kbase + (size_t)key * (HH * 64), qa0, qa1);
#pragma unroll
            for (int r = 0; r < 4; ++r)
                l_[r] += __expf(d[r] + bf2f(mb[w][quad * 4 + r][g * 16 + n16]));
        }
        wave_lds_fence();   // reads done before next kt overwrites
    }
#pragma unroll
    for (int r = 0; r < 4; ++r) {
        float ll = l_[r];
#pragma unroll
        for (int off = 1; off < 16; off <<= 1) ll += __shfl_xor(ll, off);
        l_[r] = ll;
    }
    if (n16 == 0) {
#pragma unroll
        for (int r = 0; r < 4; ++r) l_scr[w][quad * 4 + r] = l_[r];
    }
    __syncthreads();
    float linv[4];
#pragma unroll
    for (int r = 0; r < 4; ++r)
        linv[r] = 1.0f / (l_scr[h][quad * 4 + r] + l_scr[h + 4][quad * 4 + r]);

    // ---------------- PASS 2: weights, mean, PV ----------------
    f32x4 pv[3];
#pragma unroll
    for (int nb = 0; nb < 3; ++nb) pv[nb] = (f32x4){0.f, 0.f, 0.f, 0.f};

    for (int kt = 0; kt < SS / 2 / 64; ++kt) {
        const int kb = kt * 64;
#pragma unroll
        for (int rr = 0; rr < 4; ++rr) {
            const int row = rr * 4 + srow;
            int4 mz = *(const int4*)(mrow0 + (size_t)row * SS + kb);
            float4 bv = *(const float4*)(brow0 + (size_t)row * SS + kb);
            ushort4 o;
            o.x = mz.x ? f2bf(bv.x) : (ushort)MB_NEG;
            o.y = mz.y ? f2bf(bv.y) : (ushort)MB_NEG;
            o.z = mz.z ? f2bf(bv.z) : (ushort)MB_NEG;
            o.w = mz.w ? f2bf(bv.w) : (ushort)MB_NEG;
            *(ushort4*)&mb[w][row][skey] = o;
        }
        wave_lds_fence();
#pragma unroll
        for (int g = 0; g < 4; ++g) {
            const int key = kbase0 + kb + g * 16 + n16;
            f32x4 d = qk_tile(kbase + (size_t)key * (HH * 64), qa0, qa1);
#pragma unroll
            for (int r = 0; r < 4; ++r) {
                float wgt = __expf(d[r] + bf2f(mb[w][quad * 4 + r][g * 16 + n16]))
                            * linv[r];
                w_lds[w][quad * 4 + r][g * 16 + n16] = f2bf(wgt);
            }
        }
        __syncthreads();   // all 8 w-tiles complete

        // out1 mean over heads: 2 groups x 16 rows x 64 keys = 2048 elems
#pragma unroll
        for (int i = 0; i < 4; ++i) {
            const int idx = i * 512 + t;
            const int grp = idx >> 10;
            const int row = (idx >> 6) & 15;
            const int key = idx & 63;
            float s = bf2f(w_lds[grp * 4 + 0][row][key]) +
                      bf2f(w_lds[grp * 4 + 1][row][key]) +
                      bf2f(w_lds[grp * 4 + 2][row][key]) +
                      bf2f(w_lds[grp * 4 + 3][row][key]);
            out1[((size_t)(b * SS + q0 + row)) * SS + grp * (SS / 2) + kb + key] =
                s * 0.25f;
        }

        // PV from own w tile
        const short8 wa0 = *(const short8*)&w_lds[w][n16][quad * 8];
        const short8 wa1 = *(const short8*)&w_lds[w][n16][32 + quad * 8];
#pragma unroll
        for (int nb = 0; nb < 3; ++nb) {
            const ushort* vb = vT + ((size_t)(b * HH + h) * 48 + nb * 16 + n16) * SS
                               + kbase0 + kb + quad * 8;
            short8 v0 = *(const short8*)(vb);
            short8 v1 = *(const short8*)(vb + 32);
            pv[nb] = __builtin_amdgcn_mfma_f32_16x16x32_bf16(wa0, v0, pv[nb], 0, 0, 0);
            pv[nb] = __builtin_amdgcn_mfma_f32_16x16x32_bf16(wa1, v1, pv[nb], 0, 0, 0);
        }
        __syncthreads();   // before next kt overwrites w_lds
    }

    // merge PV across K-halves via LDS scratch (aliases mb)
    float* scr = (float*)&mb[0][0][0];
    if (kh == 1) {
#pragma unroll
        for (int nb = 0; nb < 3; ++nb)
            *(f32x4*)&scr[((size_t)(h * 64 + lane)) * 12 + nb * 4] = pv[nb];
    }
    __syncthreads();
    if (kh == 0) {
#pragma unroll
        for (int nb = 0; nb < 3; ++nb) {
            f32x4 po = *(const f32x4*)&scr[((size_t)(h * 64 + lane)) * 12 + nb * 4];
#pragma unroll
            for (int r = 0; r < 4; ++r)
                oattn[((size_t)(b * SS + q0 + quad * 4 + r)) * DD +
                      h * 48 + nb * 16 + n16] = pv[nb][r] + po[r];
        }
    }
}

// ---------------------------------------------------------------------------
extern "C" void kernel_launch(void* const* d_in, const int* in_sizes, int n_in,
                              void* d_out, int out_size, void* d_ws, size_t ws_size,
                              hipStream_t stream)
{
    const float* query = (const float*)d_in[0];
    const float* key   = (const float*)d_in[1];
    const float* value = (const float*)d_in[2];
    const int*   amask = (const int*)d_in[3];
    const float* bias  = (const float*)d_in[4];
    const float* Wq    = (const float*)d_in[5];
    const float* Wk    = (const float*)d_in[6];
    const float* Wv    = (const float*)d_in[7];
    const float* Wo    = (const float*)d_in[8];

    const size_t n_rows = (size_t)BB * SS;
    float* out0 = (float*)d_out;
    float* out1 = out0 + n_rows * DD;

    ushort* qpad = (ushort*)d_ws;                        // 4 MB
    ushort* kpad = qpad + n_rows * HH * 64;              // 4 MB
    ushort* vT   = kpad + n_rows * HH * 64;              // 3 MB
    float*  oattn = (float*)(vT + (size_t)BB * HH * 48 * SS);   // 6.3 MB
    float*  WTall = oattn + n_rows * DD;                 // 0.59 MB

    wt_kernel<<<dim3(6, 6, 4), 256, 0, stream>>>(Wq, Wk, Wv, Wo, WTall);

    qkv_proj_kernel<<<dim3(n_rows / 32, 3), 192, 0, stream>>>(
        query, key, value, WTall, qpad, kpad, vT);

    attn_kernel<<<dim3(BB * SS / QT), 512, 0, stream>>>(
        qpad, kpad, vT, amask, bias, out1, oattn);

    o_proj_kernel<<<dim3(n_rows / 32), 192, 0, stream>>>(
        oattn, WTall + 3 * DD * DD, out0);
}